// Round 1
// baseline (1626.793 us; speedup 1.0000x reference)
//
#include <hip/hip_runtime.h>

#define HID 128

// ---------------- degree count ----------------
__global__ void count_kernel(const int* __restrict__ dst, float* __restrict__ cnt, int E) {
    int e = blockIdx.x * blockDim.x + threadIdx.x;
    if (e < E) atomicAdd(&cnt[dst[e]], 1.0f);
}

// ---------------- scatter-add features ----------------
template<int F>
__global__ void scatter_kernel(const float* __restrict__ feat, const int* __restrict__ src,
                               const int* __restrict__ dst, float* __restrict__ agg, int E) {
    unsigned gid = blockIdx.x * blockDim.x + threadIdx.x;
    if (gid >= (unsigned)E * F) return;
    int e = gid / F;        // F is power of two -> shift
    int f = gid % F;
    atomicAdd(&agg[dst[e] * F + f], feat[src[e] * F + f]);
}

// ---------------- SAGE layer GEMM ----------------
// out[n, :] = act( (agg[n,:]/max(cnt,1)) @ Wl + bl + x[n,:] @ Wr )
// M-tile = 64 nodes, N = 128 (full), K chunks of 32. 256 threads: tm=t&15, tn=t>>4,
// each thread computes 4 rows x (4 + 4) cols.
template<int K0, int K1, bool RELU>
__global__ __launch_bounds__(256) void layer_gemm(
    const float* __restrict__ agg, const float* __restrict__ cnt,
    const float* __restrict__ xin,
    const float* __restrict__ Wl, const float* __restrict__ bl,
    const float* __restrict__ Wr,
    float* __restrict__ out, int N)
{
    __shared__ float As[64][33];       // [m][j] padded: stride 33 breaks bank conflicts
    __shared__ float Bs[32][128];
    __shared__ float invc[64];

    const int t  = threadIdx.x;
    const int tm = t & 15, tn = t >> 4;
    const int n0 = blockIdx.x * 64;

    if (t < 64) {
        int n = n0 + t;
        invc[t] = (n < N) ? 1.0f / fmaxf(cnt[n], 1.0f) : 0.0f;
    }
    __syncthreads();

    float acc[4][8] = {};

    for (int kc = 0; kc < K0 + K1; kc += 32) {
        const bool fromAgg = (kc < K0);
        const float* W = fromAgg ? (Wl + kc * HID) : (Wr + (kc - K0) * HID);
        // stage B chunk: rows kc..kc+31 of the active weight, 32x128
        for (int i = t; i < 32 * HID; i += 256)
            Bs[i >> 7][i & 127] = W[i];
        // stage A chunk: 64 nodes x 32 k-values, coalesced along k
        for (int i = t; i < 64 * 32; i += 256) {
            int m = i >> 5, j = i & 31;
            int n = n0 + m;
            float v = 0.0f;
            if (n < N) {
                if (fromAgg) v = agg[n * K0 + kc + j] * invc[m];
                else         v = xin[n * K1 + (kc - K0) + j];
            }
            As[m][j] = v;
        }
        __syncthreads();

        #pragma unroll 8
        for (int j = 0; j < 32; ++j) {
            float av[4];
            av[0] = As[tm * 4 + 0][j];
            av[1] = As[tm * 4 + 1][j];
            av[2] = As[tm * 4 + 2][j];
            av[3] = As[tm * 4 + 3][j];
            float4 b0 = *(const float4*)&Bs[j][tn * 4];
            float4 b1 = *(const float4*)&Bs[j][tn * 4 + 64];
            float bv[8] = {b0.x, b0.y, b0.z, b0.w, b1.x, b1.y, b1.z, b1.w};
            #pragma unroll
            for (int mi = 0; mi < 4; ++mi)
                #pragma unroll
                for (int ni = 0; ni < 8; ++ni)
                    acc[mi][ni] += av[mi] * bv[ni];
        }
        __syncthreads();
    }

    #pragma unroll
    for (int mi = 0; mi < 4; ++mi) {
        int n = n0 + tm * 4 + mi;
        if (n < N) {
            float4 v0, v1;
            float* p0 = (float*)&v0;
            float* p1 = (float*)&v1;
            #pragma unroll
            for (int ni = 0; ni < 4; ++ni) {
                float a = acc[mi][ni] + bl[tn * 4 + ni];
                float b = acc[mi][ni + 4] + bl[64 + tn * 4 + ni];
                if (RELU) { a = fmaxf(a, 0.0f); b = fmaxf(b, 0.0f); }
                p0[ni] = a; p1[ni] = b;
            }
            *(float4*)&out[n * HID + tn * 4]      = v0;
            *(float4*)&out[n * HID + 64 + tn * 4] = v1;
        }
    }
}

// ---------------- classify: fused feats@W1 + relu + @W2 + b2 ----------------
// feats[e] = [h1[fsrc[e]], h1[fdst[e]], eattr[e]]  (128+128+32 = 288)
__global__ __launch_bounds__(256) void classify_kernel(
    const float* __restrict__ h1, const int* __restrict__ fsrc, const int* __restrict__ fdst,
    const float* __restrict__ eattr,
    const float* __restrict__ W1, const float* __restrict__ b1,
    const float* __restrict__ W2, const float* __restrict__ b2,
    float* __restrict__ out, int Ef)
{
    __shared__ float As[64][33];
    __shared__ float Bs[32][128];
    __shared__ float red[64][17];

    const int t  = threadIdx.x;
    const int tm = t & 15, tn = t >> 4;
    const int e0 = blockIdx.x * 64;

    float acc[4][8] = {};

    for (int kc = 0; kc < 288; kc += 32) {
        for (int i = t; i < 32 * 128; i += 256)
            Bs[i >> 7][i & 127] = W1[kc * 128 + i];
        for (int i = t; i < 64 * 32; i += 256) {
            int m = i >> 5, j = i & 31;
            int e = e0 + m;
            float v = 0.0f;
            if (e < Ef) {
                int jj = kc + j;   // chunk boundaries align with source boundaries
                if (jj < 128)      v = h1[fsrc[e] * 128 + jj];
                else if (jj < 256) v = h1[fdst[e] * 128 + (jj - 128)];
                else               v = eattr[e * 32 + (jj - 256)];
            }
            As[m][j] = v;
        }
        __syncthreads();

        #pragma unroll 8
        for (int j = 0; j < 32; ++j) {
            float av[4];
            av[0] = As[tm * 4 + 0][j];
            av[1] = As[tm * 4 + 1][j];
            av[2] = As[tm * 4 + 2][j];
            av[3] = As[tm * 4 + 3][j];
            float4 b0 = *(const float4*)&Bs[j][tn * 4];
            float4 b1v = *(const float4*)&Bs[j][tn * 4 + 64];
            float bv[8] = {b0.x, b0.y, b0.z, b0.w, b1v.x, b1v.y, b1v.z, b1v.w};
            #pragma unroll
            for (int mi = 0; mi < 4; ++mi)
                #pragma unroll
                for (int ni = 0; ni < 8; ++ni)
                    acc[mi][ni] += av[mi] * bv[ni];
        }
        __syncthreads();
    }

    // epilogue: relu(acc + b1) dot W2, reduce across the 16 tn groups
    #pragma unroll
    for (int mi = 0; mi < 4; ++mi) {
        float s = 0.0f;
        #pragma unroll
        for (int ni = 0; ni < 8; ++ni) {
            int col = (ni < 4) ? (tn * 4 + ni) : (64 + tn * 4 + (ni - 4));
            float v = acc[mi][ni] + b1[col];
            v = fmaxf(v, 0.0f);
            s += v * W2[col];
        }
        red[tm * 4 + mi][tn] = s;
    }
    __syncthreads();
    if (t < 64) {
        float s = 0.0f;
        #pragma unroll
        for (int i = 0; i < 16; ++i) s += red[t][i];
        int e = e0 + t;
        if (e < Ef) out[e] = s + b2[0];
    }
}

extern "C" void kernel_launch(void* const* d_in, const int* in_sizes, int n_in,
                              void* d_out, int out_size, void* d_ws, size_t ws_size,
                              hipStream_t stream) {
    const float* x     = (const float*)d_in[0];
    const int*   ei    = (const int*)d_in[1];
    const int*   fei   = (const int*)d_in[2];
    const float* eattr = (const float*)d_in[3];
    const float* Wl0   = (const float*)d_in[4];
    const float* bl0   = (const float*)d_in[5];
    const float* Wr0   = (const float*)d_in[6];
    const float* Wl1   = (const float*)d_in[7];
    const float* bl1   = (const float*)d_in[8];
    const float* Wr1   = (const float*)d_in[9];
    const float* W1    = (const float*)d_in[10];
    const float* b1    = (const float*)d_in[11];
    const float* W2    = (const float*)d_in[12];
    const float* b2    = (const float*)d_in[13];

    const int E  = in_sizes[1] / 2;
    const int Ef = in_sizes[2] / 2;
    const int N  = in_sizes[0] / 64;

    const int* src  = ei;
    const int* dst  = ei + E;
    const int* fsrc = fei;
    const int* fdst = fei + Ef;

    float* wsf = (float*)d_ws;
    float* cnt = wsf;                         // N floats (pad region to 128K floats)
    float* agg = wsf + (1 << 17);             // N*128 floats max
    float* h   = agg + (size_t)N * 128;       // N*128
    float* h1  = h   + (size_t)N * 128;       // N*128
    float* out = (float*)d_out;

    hipMemsetAsync(cnt, 0, (size_t)N * 4, stream);
    hipMemsetAsync(agg, 0, (size_t)N * 64 * 4, stream);

    count_kernel<<<(E + 255) / 256, 256, 0, stream>>>(dst, cnt, E);

    {   // layer 0 scatter: x[src] -> agg (64 feats)
        unsigned total = (unsigned)E * 64;
        scatter_kernel<64><<<(total + 255) / 256, 256, 0, stream>>>(x, src, dst, agg, E);
    }
    layer_gemm<64, 64, true><<<(N + 63) / 64, 256, 0, stream>>>(
        agg, cnt, x, Wl0, bl0, Wr0, h, N);

    hipMemsetAsync(agg, 0, (size_t)N * 128 * 4, stream);
    {   // layer 1 scatter: h[src] -> agg (128 feats)
        unsigned total = (unsigned)E * 128;
        scatter_kernel<128><<<(total + 255) / 256, 256, 0, stream>>>(h, src, dst, agg, E);
    }
    layer_gemm<128, 128, false><<<(N + 63) / 64, 256, 0, stream>>>(
        agg, cnt, h, Wl1, bl1, Wr1, h1, N);

    classify_kernel<<<(Ef + 63) / 64, 256, 0, stream>>>(
        h1, fsrc, fdst, eattr, W1, b1, W2, b2, out, Ef);
}

// Round 2
// 1109.769 us; speedup vs baseline: 1.4659x; 1.4659x over previous
//
#include <hip/hip_runtime.h>

#define HID 128

typedef __attribute__((ext_vector_type(8))) short bf16x8;
typedef __attribute__((ext_vector_type(4))) float f32x4;

__device__ inline unsigned short f2bf(float f) {
    unsigned u = __float_as_uint(f);
    unsigned r = (u + 0x7FFF + ((u >> 16) & 1)) >> 16;   // RNE
    return (unsigned short)r;
}
__device__ inline float bf2f(unsigned short h) { return __uint_as_float((unsigned)h << 16); }

// ---------------- degree count ----------------
__global__ void count_kernel(const int* __restrict__ dst, float* __restrict__ cnt, int E) {
    int e = blockIdx.x * blockDim.x + threadIdx.x;
    if (e < E) atomicAdd(&cnt[dst[e]], 1.0f);
}

// ---------------- scatter-add features ----------------
template<int F>
__global__ void scatter_kernel(const float* __restrict__ feat, const int* __restrict__ src,
                               const int* __restrict__ dst, float* __restrict__ agg, int E) {
    unsigned gid = blockIdx.x * blockDim.x + threadIdx.x;
    if (gid >= (unsigned)E * F) return;
    int e = gid / F;
    int f = gid % F;
    atomicAdd(&agg[dst[e] * F + f], feat[src[e] * F + f]);
}

// ---------------- SAGE layer GEMM (fp32 VALU, unchanged this round) ----------------
template<int K0, int K1, bool RELU>
__global__ __launch_bounds__(256) void layer_gemm(
    const float* __restrict__ agg, const float* __restrict__ cnt,
    const float* __restrict__ xin,
    const float* __restrict__ Wl, const float* __restrict__ bl,
    const float* __restrict__ Wr,
    float* __restrict__ out, int N)
{
    __shared__ float As[64][33];
    __shared__ float Bs[32][128];
    __shared__ float invc[64];

    const int t  = threadIdx.x;
    const int tm = t & 15, tn = t >> 4;
    const int n0 = blockIdx.x * 64;

    if (t < 64) {
        int n = n0 + t;
        invc[t] = (n < N) ? 1.0f / fmaxf(cnt[n], 1.0f) : 0.0f;
    }
    __syncthreads();

    float acc[4][8] = {};

    for (int kc = 0; kc < K0 + K1; kc += 32) {
        const bool fromAgg = (kc < K0);
        const float* W = fromAgg ? (Wl + kc * HID) : (Wr + (kc - K0) * HID);
        for (int i = t; i < 32 * HID; i += 256)
            Bs[i >> 7][i & 127] = W[i];
        for (int i = t; i < 64 * 32; i += 256) {
            int m = i >> 5, j = i & 31;
            int n = n0 + m;
            float v = 0.0f;
            if (n < N) {
                if (fromAgg) v = agg[n * K0 + kc + j] * invc[m];
                else         v = xin[n * K1 + (kc - K0) + j];
            }
            As[m][j] = v;
        }
        __syncthreads();

        #pragma unroll 8
        for (int j = 0; j < 32; ++j) {
            float av[4];
            av[0] = As[tm * 4 + 0][j];
            av[1] = As[tm * 4 + 1][j];
            av[2] = As[tm * 4 + 2][j];
            av[3] = As[tm * 4 + 3][j];
            float4 b0 = *(const float4*)&Bs[j][tn * 4];
            float4 b1 = *(const float4*)&Bs[j][tn * 4 + 64];
            float bv[8] = {b0.x, b0.y, b0.z, b0.w, b1.x, b1.y, b1.z, b1.w};
            #pragma unroll
            for (int mi = 0; mi < 4; ++mi)
                #pragma unroll
                for (int ni = 0; ni < 8; ++ni)
                    acc[mi][ni] += av[mi] * bv[ni];
        }
        __syncthreads();
    }

    #pragma unroll
    for (int mi = 0; mi < 4; ++mi) {
        int n = n0 + tm * 4 + mi;
        if (n < N) {
            float4 v0, v1;
            float* p0 = (float*)&v0;
            float* p1 = (float*)&v1;
            #pragma unroll
            for (int ni = 0; ni < 4; ++ni) {
                float a = acc[mi][ni] + bl[tn * 4 + ni];
                float b = acc[mi][ni + 4] + bl[64 + tn * 4 + ni];
                if (RELU) { a = fmaxf(a, 0.0f); b = fmaxf(b, 0.0f); }
                p0[ni] = a; p1[ni] = b;
            }
            *(float4*)&out[n * HID + tn * 4]      = v0;
            *(float4*)&out[n * HID + 64 + tn * 4] = v1;
        }
    }
}

// ---------------- split fp32 -> bf16 hi/lo (vectorized x4) ----------------
__global__ void split_bf16(const float* __restrict__ in, unsigned short* __restrict__ hi,
                           unsigned short* __restrict__ lo, int n4) {
    int i = blockIdx.x * blockDim.x + threadIdx.x;
    if (i >= n4) return;
    float4 v = ((const float4*)in)[i];
    float f[4] = {v.x, v.y, v.z, v.w};
    ushort4 h, l;
    unsigned short* hp = (unsigned short*)&h;
    unsigned short* lp = (unsigned short*)&l;
    #pragma unroll
    for (int j = 0; j < 4; ++j) {
        unsigned short hb = f2bf(f[j]);
        hp[j] = hb;
        lp[j] = f2bf(f[j] - bf2f(hb));
    }
    ((ushort4*)hi)[i] = h;
    ((ushort4*)lo)[i] = l;
}

// ---------------- W1 -> fragment-linear bf16 hi/lo ----------------
// layout: idx = c*4096 + nt*512 + q*128 + r*8 + jj  for element (k = c*32+q*8+jj, n = nt*16+r)
__global__ void split_w1(const float* __restrict__ W1, unsigned short* __restrict__ hi,
                         unsigned short* __restrict__ lo) {
    int tid = blockIdx.x * blockDim.x + threadIdx.x;
    if (tid >= 288 * 128) return;
    int k = tid >> 7, n = tid & 127;
    int c = k >> 5, ko = k & 31, q = ko >> 3, jj = ko & 7;
    int nt = n >> 4, r = n & 15;
    int idx = c * 4096 + nt * 512 + q * 128 + r * 8 + jj;
    float v = W1[tid];
    unsigned short hb = f2bf(v);
    hi[idx] = hb;
    lo[idx] = f2bf(v - bf2f(hb));
}

// ---------------- classify: split-bf16 MFMA, all-register, no LDS staging ----------------
// Block: 256 thr = 4 waves; tile = 128 edges x 128 cols. Per wave: 32 edges (2 m-tiles) x 8 n-tiles.
// K = 288 = 9 chunks of 32: chunks 0-3 h1[fsrc], 4-7 h1[fdst], 8 eattr (fp32, converted in-reg).
__global__ __launch_bounds__(256) void classify_mfma(
    const unsigned short* __restrict__ h1_hi, const unsigned short* __restrict__ h1_lo,
    const int* __restrict__ fsrc, const int* __restrict__ fdst,
    const float* __restrict__ eattr,
    const unsigned short* __restrict__ w1_hi, const unsigned short* __restrict__ w1_lo,
    const float* __restrict__ b1, const float* __restrict__ W2, const float* __restrict__ b2,
    float* __restrict__ out, int Ef)
{
    __shared__ int es[128], ed[128];

    const int t = threadIdx.x;
    const int wave = t >> 6, lane = t & 63;
    const int l15 = lane & 15, quad = lane >> 4;
    const int e0 = blockIdx.x * 128;

    if (t < 128) {
        int e = e0 + t;
        int ec = (e < Ef) ? e : (Ef - 1);
        es[t] = fsrc[ec];
        ed[t] = fdst[ec];
    }
    __syncthreads();

    float b1v[8], w2v[8];
    #pragma unroll
    for (int nt = 0; nt < 8; ++nt) {
        b1v[nt] = b1[nt * 16 + l15];
        w2v[nt] = W2[nt * 16 + l15];
    }
    const float b2s = b2[0];

    f32x4 acc[2][8] = {};

    const int m0 = wave * 32 + l15;   // m for mt=0 is m0, mt=1 is m0+16

    #pragma unroll
    for (int kc_i = 0; kc_i < 9; ++kc_i) {
        bf16x8 ah[2], al[2];
        if (kc_i < 8) {
            #pragma unroll
            for (int mt = 0; mt < 2; ++mt) {
                int node = (kc_i < 4) ? es[m0 + mt * 16] : ed[m0 + mt * 16];
                int kloc = (kc_i & 3) * 32 + quad * 8;
                ah[mt] = *(const bf16x8*)(h1_hi + (size_t)node * 128 + kloc);
                al[mt] = *(const bf16x8*)(h1_lo + (size_t)node * 128 + kloc);
            }
        } else {
            #pragma unroll
            for (int mt = 0; mt < 2; ++mt) {
                int e = e0 + wave * 32 + mt * 16 + l15;
                if (e >= Ef) e = Ef - 1;
                const float* pe = eattr + (size_t)e * 32 + quad * 8;
                float4 f0 = *(const float4*)pe;
                float4 f1 = *(const float4*)(pe + 4);
                float fv[8] = {f0.x, f0.y, f0.z, f0.w, f1.x, f1.y, f1.z, f1.w};
                #pragma unroll
                for (int j = 0; j < 8; ++j) {
                    unsigned short hb = f2bf(fv[j]);
                    ah[mt][j] = (short)hb;
                    al[mt][j] = (short)f2bf(fv[j] - bf2f(hb));
                }
            }
        }
        const unsigned short* wh = w1_hi + kc_i * 4096 + lane * 8;
        const unsigned short* wl = w1_lo + kc_i * 4096 + lane * 8;
        #pragma unroll
        for (int nt = 0; nt < 8; ++nt) {
            bf16x8 bh = *(const bf16x8*)(wh + nt * 512);
            bf16x8 bl = *(const bf16x8*)(wl + nt * 512);
            #pragma unroll
            for (int mt = 0; mt < 2; ++mt) {
                acc[mt][nt] = __builtin_amdgcn_mfma_f32_16x16x32_bf16(ah[mt], bh, acc[mt][nt], 0, 0, 0);
                acc[mt][nt] = __builtin_amdgcn_mfma_f32_16x16x32_bf16(ah[mt], bl, acc[mt][nt], 0, 0, 0);
                acc[mt][nt] = __builtin_amdgcn_mfma_f32_16x16x32_bf16(al[mt], bh, acc[mt][nt], 0, 0, 0);
            }
        }
    }

    // epilogue: relu(acc + b1) . W2, reduce over the 16 lanes (l15) holding different cols
    #pragma unroll
    for (int mt = 0; mt < 2; ++mt) {
        #pragma unroll
        for (int reg = 0; reg < 4; ++reg) {
            float s = 0.0f;
            #pragma unroll
            for (int nt = 0; nt < 8; ++nt) {
                float v = acc[mt][nt][reg] + b1v[nt];
                s += fmaxf(v, 0.0f) * w2v[nt];
            }
            s += __shfl_xor(s, 1);
            s += __shfl_xor(s, 2);
            s += __shfl_xor(s, 4);
            s += __shfl_xor(s, 8);
            if (l15 == 0) {
                int e = e0 + wave * 32 + mt * 16 + quad * 4 + reg;
                if (e < Ef) out[e] = s + b2s;
            }
        }
    }
}

extern "C" void kernel_launch(void* const* d_in, const int* in_sizes, int n_in,
                              void* d_out, int out_size, void* d_ws, size_t ws_size,
                              hipStream_t stream) {
    const float* x     = (const float*)d_in[0];
    const int*   ei    = (const int*)d_in[1];
    const int*   fei   = (const int*)d_in[2];
    const float* eattr = (const float*)d_in[3];
    const float* Wl0   = (const float*)d_in[4];
    const float* bl0   = (const float*)d_in[5];
    const float* Wr0   = (const float*)d_in[6];
    const float* Wl1   = (const float*)d_in[7];
    const float* bl1   = (const float*)d_in[8];
    const float* Wr1   = (const float*)d_in[9];
    const float* W1    = (const float*)d_in[10];
    const float* b1    = (const float*)d_in[11];
    const float* W2    = (const float*)d_in[12];
    const float* b2    = (const float*)d_in[13];

    const int E  = in_sizes[1] / 2;
    const int Ef = in_sizes[2] / 2;
    const int N  = in_sizes[0] / 64;

    const int* src  = ei;
    const int* dst  = ei + E;
    const int* fsrc = fei;
    const int* fdst = fei + Ef;

    // workspace layout (floats unless noted):
    // [0, N)              cnt
    // [N, ...)            W1f_hi (36864 ush) + W1f_lo (36864 ush)  = 36864 floats-equiv... (147456 B)
    // agg at float offset N + 36864  (36864 floats cover both ush arrays)
    float* wsf = (float*)d_ws;
    float* cnt = wsf;
    unsigned short* w1f_hi = (unsigned short*)(wsf + N);          // N*4 byte offset, 16B-aligned (N=100000)
    unsigned short* w1f_lo = w1f_hi + 288 * 128;
    float* agg = wsf + N + 36864;                                  // byte offset 547456, 16B aligned
    float* h   = agg + (size_t)N * 128;
    float* h1  = h   + (size_t)N * 128;
    unsigned short* h1_hi = (unsigned short*)agg;                  // overlay: agg dead after layer_gemm1
    unsigned short* h1_lo = h1_hi + (size_t)N * 128;
    float* out = (float*)d_out;

    hipMemsetAsync(cnt, 0, (size_t)N * 4, stream);
    hipMemsetAsync(agg, 0, (size_t)N * 64 * 4, stream);

    split_w1<<<(288 * 128 + 255) / 256, 256, 0, stream>>>(W1, w1f_hi, w1f_lo);
    count_kernel<<<(E + 255) / 256, 256, 0, stream>>>(dst, cnt, E);

    {   // layer 0 scatter: x[src] -> agg (64 feats)
        unsigned total = (unsigned)E * 64;
        scatter_kernel<64><<<(total + 255) / 256, 256, 0, stream>>>(x, src, dst, agg, E);
    }
    layer_gemm<64, 64, true><<<(N + 63) / 64, 256, 0, stream>>>(
        agg, cnt, x, Wl0, bl0, Wr0, h, N);

    hipMemsetAsync(agg, 0, (size_t)N * 128 * 4, stream);
    {   // layer 1 scatter: h[src] -> agg (128 feats)
        unsigned total = (unsigned)E * 128;
        scatter_kernel<128><<<(total + 255) / 256, 256, 0, stream>>>(h, src, dst, agg, E);
    }
    layer_gemm<128, 128, false><<<(N + 63) / 64, 256, 0, stream>>>(
        agg, cnt, h, Wl1, bl1, Wr1, h1, N);

    // pre-split h1 into bf16 hi/lo (overlaying dead agg region)
    split_bf16<<<((N * 128 / 4) + 255) / 256, 256, 0, stream>>>(h1, h1_hi, h1_lo, N * 128 / 4);

    classify_mfma<<<(Ef + 127) / 128, 256, 0, stream>>>(
        h1_hi, h1_lo, fsrc, fdst, eattr, w1f_hi, w1f_lo, b1, W2, b2, out, Ef);
}

// Round 3
// 726.168 us; speedup vs baseline: 2.2402x; 1.5283x over previous
//
#include <hip/hip_runtime.h>

#define HID 128

typedef __attribute__((ext_vector_type(8))) short bf16x8;
typedef __attribute__((ext_vector_type(4))) float f32x4;

__device__ inline unsigned short f2bf(float f) {
    unsigned u = __float_as_uint(f);
    unsigned r = (u + 0x7FFF + ((u >> 16) & 1)) >> 16;   // RNE
    return (unsigned short)r;
}
__device__ inline float bf2f(unsigned short h) { return __uint_as_float((unsigned)h << 16); }

// ---------------- CSR build ----------------
__global__ void degree_kernel(const int* __restrict__ dst, int* __restrict__ deg, int E) {
    int e = blockIdx.x * blockDim.x + threadIdx.x;
    if (e < E) atomicAdd(&deg[dst[e]], 1);
}

// pass 1: per-1024-chunk sums
__global__ void scan_reduce(const int* __restrict__ deg, int* __restrict__ bsum, int N) {
    __shared__ int sd[256];
    int b = blockIdx.x, t = threadIdx.x;
    int base = b * 1024, s = 0;
    for (int i = t; i < 1024; i += 256) {
        int idx = base + i;
        s += (idx < N) ? deg[idx] : 0;
    }
    sd[t] = s; __syncthreads();
    for (int st = 128; st > 0; st >>= 1) {
        if (t < st) sd[t] += sd[t + st];
        __syncthreads();
    }
    if (t == 0) bsum[b] = sd[0];
}

// pass 2: exclusive scan of block sums (single block, nb <= 256)
__global__ void scan_bsum(int* __restrict__ bsum, int nb) {
    __shared__ int s[256];
    int t = threadIdx.x;
    int v = (t < nb) ? bsum[t] : 0;
    s[t] = v; __syncthreads();
    for (int st = 1; st < 256; st <<= 1) {
        int add = (t >= st) ? s[t - st] : 0;
        __syncthreads();
        s[t] += add;
        __syncthreads();
    }
    if (t < nb) bsum[t] = s[t] - v;   // exclusive
}

// pass 3: final offsets; also init pos = off
__global__ void scan_final(const int* __restrict__ deg, const int* __restrict__ bsum,
                           int* __restrict__ off, int* __restrict__ pos, int N, int E) {
    __shared__ int ts[256];
    int b = blockIdx.x, t = threadIdx.x, base = b * 1024;
    int v[4], s = 0;
    #pragma unroll
    for (int j = 0; j < 4; ++j) {
        int idx = base + t * 4 + j;
        v[j] = (idx < N) ? deg[idx] : 0;
        s += v[j];
    }
    ts[t] = s; __syncthreads();
    int mine = s;
    for (int st = 1; st < 256; st <<= 1) {
        int add = (t >= st) ? ts[t - st] : 0;
        __syncthreads();
        ts[t] += add;
        __syncthreads();
    }
    int ex = ts[t] - mine + bsum[b];
    #pragma unroll
    for (int j = 0; j < 4; ++j) {
        int idx = base + t * 4 + j;
        if (idx < N) { off[idx] = ex; pos[idx] = ex; }
        ex += v[j];
    }
    if (b == 0 && t == 0) off[N] = E;
}

__global__ void bucket_kernel(const int* __restrict__ src, const int* __restrict__ dst,
                              int* __restrict__ pos, int* __restrict__ eid, int E) {
    int e = blockIdx.x * blockDim.x + threadIdx.x;
    if (e < E) {
        int p = atomicAdd(&pos[dst[e]], 1);
        eid[p] = src[e];
    }
}

// ---------------- gather aggregate (mean), one wave per node ----------------
template<int F>
__global__ __launch_bounds__(256) void aggregate_kernel(
    const float* __restrict__ feat, const int* __restrict__ eid,
    const int* __restrict__ off, float* __restrict__ agg, int N)
{
    int wave = threadIdx.x >> 6, lane = threadIdx.x & 63;
    int n = blockIdx.x * 4 + wave;
    if (n >= N) return;
    int s0 = __builtin_amdgcn_readfirstlane(off[n]);
    int s1 = __builtin_amdgcn_readfirstlane(off[n + 1]);

    if (F == 128) {
        float ax = 0.0f, ay = 0.0f;
        int i = s0;
        for (; i + 1 < s1; i += 2) {
            int sa = eid[i], sb = eid[i + 1];
            float2 va = *(const float2*)&feat[(size_t)sa * 128 + lane * 2];
            float2 vb = *(const float2*)&feat[(size_t)sb * 128 + lane * 2];
            ax += va.x + vb.x; ay += va.y + vb.y;
        }
        if (i < s1) {
            float2 va = *(const float2*)&feat[(size_t)eid[i] * 128 + lane * 2];
            ax += va.x; ay += va.y;
        }
        float inv = (s1 > s0) ? 1.0f / (float)(s1 - s0) : 0.0f;
        float2 r; r.x = ax * inv; r.y = ay * inv;
        *(float2*)&agg[(size_t)n * 128 + lane * 2] = r;
    } else {
        float a = 0.0f;
        int i = s0;
        for (; i + 1 < s1; i += 2) {
            int sa = eid[i], sb = eid[i + 1];
            a += feat[(size_t)sa * 64 + lane] + feat[(size_t)sb * 64 + lane];
        }
        if (i < s1) a += feat[(size_t)eid[i] * 64 + lane];
        float inv = (s1 > s0) ? 1.0f / (float)(s1 - s0) : 0.0f;
        agg[(size_t)n * 64 + lane] = a * inv;
    }
}

// ---------------- SAGE layer GEMM (fp32 VALU; agg already holds the mean) ----------------
template<int K0, int K1, bool RELU>
__global__ __launch_bounds__(256) void layer_gemm(
    const float* __restrict__ agg, const float* __restrict__ xin,
    const float* __restrict__ Wl, const float* __restrict__ bl,
    const float* __restrict__ Wr,
    float* __restrict__ out, int N)
{
    __shared__ float As[64][33];
    __shared__ float Bs[32][128];

    const int t  = threadIdx.x;
    const int tm = t & 15, tn = t >> 4;
    const int n0 = blockIdx.x * 64;

    float acc[4][8] = {};

    for (int kc = 0; kc < K0 + K1; kc += 32) {
        const bool fromAgg = (kc < K0);
        const float* W = fromAgg ? (Wl + kc * HID) : (Wr + (kc - K0) * HID);
        for (int i = t; i < 32 * HID; i += 256)
            Bs[i >> 7][i & 127] = W[i];
        for (int i = t; i < 64 * 32; i += 256) {
            int m = i >> 5, j = i & 31;
            int n = n0 + m;
            float v = 0.0f;
            if (n < N) {
                if (fromAgg) v = agg[n * K0 + kc + j];
                else         v = xin[n * K1 + (kc - K0) + j];
            }
            As[m][j] = v;
        }
        __syncthreads();

        #pragma unroll 8
        for (int j = 0; j < 32; ++j) {
            float av[4];
            av[0] = As[tm * 4 + 0][j];
            av[1] = As[tm * 4 + 1][j];
            av[2] = As[tm * 4 + 2][j];
            av[3] = As[tm * 4 + 3][j];
            float4 b0 = *(const float4*)&Bs[j][tn * 4];
            float4 b1 = *(const float4*)&Bs[j][tn * 4 + 64];
            float bv[8] = {b0.x, b0.y, b0.z, b0.w, b1.x, b1.y, b1.z, b1.w};
            #pragma unroll
            for (int mi = 0; mi < 4; ++mi)
                #pragma unroll
                for (int ni = 0; ni < 8; ++ni)
                    acc[mi][ni] += av[mi] * bv[ni];
        }
        __syncthreads();
    }

    #pragma unroll
    for (int mi = 0; mi < 4; ++mi) {
        int n = n0 + tm * 4 + mi;
        if (n < N) {
            float4 v0, v1;
            float* p0 = (float*)&v0;
            float* p1 = (float*)&v1;
            #pragma unroll
            for (int ni = 0; ni < 4; ++ni) {
                float a = acc[mi][ni] + bl[tn * 4 + ni];
                float b = acc[mi][ni + 4] + bl[64 + tn * 4 + ni];
                if (RELU) { a = fmaxf(a, 0.0f); b = fmaxf(b, 0.0f); }
                p0[ni] = a; p1[ni] = b;
            }
            *(float4*)&out[n * HID + tn * 4]      = v0;
            *(float4*)&out[n * HID + 64 + tn * 4] = v1;
        }
    }
}

// ---------------- split fp32 -> bf16 hi/lo (vectorized x4) ----------------
__global__ void split_bf16(const float* __restrict__ in, unsigned short* __restrict__ hi,
                           unsigned short* __restrict__ lo, int n4) {
    int i = blockIdx.x * blockDim.x + threadIdx.x;
    if (i >= n4) return;
    float4 v = ((const float4*)in)[i];
    float f[4] = {v.x, v.y, v.z, v.w};
    ushort4 h, l;
    unsigned short* hp = (unsigned short*)&h;
    unsigned short* lp = (unsigned short*)&l;
    #pragma unroll
    for (int j = 0; j < 4; ++j) {
        unsigned short hb = f2bf(f[j]);
        hp[j] = hb;
        lp[j] = f2bf(f[j] - bf2f(hb));
    }
    ((ushort4*)hi)[i] = h;
    ((ushort4*)lo)[i] = l;
}

// ---------------- W1 -> fragment-linear bf16 hi/lo ----------------
__global__ void split_w1(const float* __restrict__ W1, unsigned short* __restrict__ hi,
                         unsigned short* __restrict__ lo) {
    int tid = blockIdx.x * blockDim.x + threadIdx.x;
    if (tid >= 288 * 128) return;
    int k = tid >> 7, n = tid & 127;
    int c = k >> 5, ko = k & 31, q = ko >> 3, jj = ko & 7;
    int nt = n >> 4, r = n & 15;
    int idx = c * 4096 + nt * 512 + q * 128 + r * 8 + jj;
    float v = W1[tid];
    unsigned short hb = f2bf(v);
    hi[idx] = hb;
    lo[idx] = f2bf(v - bf2f(hb));
}

// ---------------- classify: split-bf16 MFMA, all-register ----------------
__global__ __launch_bounds__(256) void classify_mfma(
    const unsigned short* __restrict__ h1_hi, const unsigned short* __restrict__ h1_lo,
    const int* __restrict__ fsrc, const int* __restrict__ fdst,
    const float* __restrict__ eattr,
    const unsigned short* __restrict__ w1_hi, const unsigned short* __restrict__ w1_lo,
    const float* __restrict__ b1, const float* __restrict__ W2, const float* __restrict__ b2,
    float* __restrict__ out, int Ef)
{
    __shared__ int es[128], ed[128];

    const int t = threadIdx.x;
    const int wave = t >> 6, lane = t & 63;
    const int l15 = lane & 15, quad = lane >> 4;
    const int e0 = blockIdx.x * 128;

    if (t < 128) {
        int e = e0 + t;
        int ec = (e < Ef) ? e : (Ef - 1);
        es[t] = fsrc[ec];
        ed[t] = fdst[ec];
    }
    __syncthreads();

    float b1v[8], w2v[8];
    #pragma unroll
    for (int nt = 0; nt < 8; ++nt) {
        b1v[nt] = b1[nt * 16 + l15];
        w2v[nt] = W2[nt * 16 + l15];
    }
    const float b2s = b2[0];

    f32x4 acc[2][8] = {};

    const int m0 = wave * 32 + l15;

    #pragma unroll
    for (int kc_i = 0; kc_i < 9; ++kc_i) {
        bf16x8 ah[2], al[2];
        if (kc_i < 8) {
            #pragma unroll
            for (int mt = 0; mt < 2; ++mt) {
                int node = (kc_i < 4) ? es[m0 + mt * 16] : ed[m0 + mt * 16];
                int kloc = (kc_i & 3) * 32 + quad * 8;
                ah[mt] = *(const bf16x8*)(h1_hi + (size_t)node * 128 + kloc);
                al[mt] = *(const bf16x8*)(h1_lo + (size_t)node * 128 + kloc);
            }
        } else {
            #pragma unroll
            for (int mt = 0; mt < 2; ++mt) {
                int e = e0 + wave * 32 + mt * 16 + l15;
                if (e >= Ef) e = Ef - 1;
                const float* pe = eattr + (size_t)e * 32 + quad * 8;
                float4 f0 = *(const float4*)pe;
                float4 f1 = *(const float4*)(pe + 4);
                float fv[8] = {f0.x, f0.y, f0.z, f0.w, f1.x, f1.y, f1.z, f1.w};
                #pragma unroll
                for (int j = 0; j < 8; ++j) {
                    unsigned short hb = f2bf(fv[j]);
                    ah[mt][j] = (short)hb;
                    al[mt][j] = (short)f2bf(fv[j] - bf2f(hb));
                }
            }
        }
        const unsigned short* wh = w1_hi + kc_i * 4096 + lane * 8;
        const unsigned short* wl = w1_lo + kc_i * 4096 + lane * 8;
        #pragma unroll
        for (int nt = 0; nt < 8; ++nt) {
            bf16x8 bh = *(const bf16x8*)(wh + nt * 512);
            bf16x8 bl = *(const bf16x8*)(wl + nt * 512);
            #pragma unroll
            for (int mt = 0; mt < 2; ++mt) {
                acc[mt][nt] = __builtin_amdgcn_mfma_f32_16x16x32_bf16(ah[mt], bh, acc[mt][nt], 0, 0, 0);
                acc[mt][nt] = __builtin_amdgcn_mfma_f32_16x16x32_bf16(ah[mt], bl, acc[mt][nt], 0, 0, 0);
                acc[mt][nt] = __builtin_amdgcn_mfma_f32_16x16x32_bf16(al[mt], bh, acc[mt][nt], 0, 0, 0);
            }
        }
    }

    #pragma unroll
    for (int mt = 0; mt < 2; ++mt) {
        #pragma unroll
        for (int reg = 0; reg < 4; ++reg) {
            float s = 0.0f;
            #pragma unroll
            for (int nt = 0; nt < 8; ++nt) {
                float v = acc[mt][nt][reg] + b1v[nt];
                s += fmaxf(v, 0.0f) * w2v[nt];
            }
            s += __shfl_xor(s, 1);
            s += __shfl_xor(s, 2);
            s += __shfl_xor(s, 4);
            s += __shfl_xor(s, 8);
            if (l15 == 0) {
                int e = e0 + wave * 32 + mt * 16 + quad * 4 + reg;
                if (e < Ef) out[e] = s + b2s;
            }
        }
    }
}

extern "C" void kernel_launch(void* const* d_in, const int* in_sizes, int n_in,
                              void* d_out, int out_size, void* d_ws, size_t ws_size,
                              hipStream_t stream) {
    const float* x     = (const float*)d_in[0];
    const int*   ei    = (const int*)d_in[1];
    const int*   fei   = (const int*)d_in[2];
    const float* eattr = (const float*)d_in[3];
    const float* Wl0   = (const float*)d_in[4];
    const float* bl0   = (const float*)d_in[5];
    const float* Wr0   = (const float*)d_in[6];
    const float* Wl1   = (const float*)d_in[7];
    const float* bl1   = (const float*)d_in[8];
    const float* Wr1   = (const float*)d_in[9];
    const float* W1    = (const float*)d_in[10];
    const float* b1    = (const float*)d_in[11];
    const float* W2    = (const float*)d_in[12];
    const float* b2    = (const float*)d_in[13];

    const int E  = in_sizes[1] / 2;
    const int Ef = in_sizes[2] / 2;
    const int N  = in_sizes[0] / 64;

    const int* src  = ei;
    const int* dst  = ei + E;
    const int* fsrc = fei;
    const int* fdst = fei + Ef;

    // workspace layout (units: floats)
    float* wsf = (float*)d_ws;
    size_t o = 0;
    int* deg  = (int*)(wsf + o); o += 131072;          // N <= 131072
    int* off  = (int*)(wsf + o); o += 131072;          // N+1
    int* pos  = (int*)(wsf + o); o += 131072;          // N+1
    int* bsum = (int*)(wsf + o); o += 256;
    int* eid  = (int*)(wsf + o); o += 1 << 20;         // E <= 1M
    unsigned short* w1f_hi = (unsigned short*)(wsf + o); o += 18432;  // 288*128 ush
    unsigned short* w1f_lo = (unsigned short*)(wsf + o); o += 18432;
    float* agg = wsf + o; o += (size_t)N * 128;
    float* h   = wsf + o; o += (size_t)N * 128;
    float* h1  = wsf + o; o += (size_t)N * 128;
    unsigned short* h1_hi = (unsigned short*)agg;      // overlay: agg dead after layer_gemm1
    unsigned short* h1_lo = h1_hi + (size_t)N * 128;
    float* out = (float*)d_out;

    const int nb = (N + 1023) / 1024;

    hipMemsetAsync(deg, 0, (size_t)N * 4, stream);
    degree_kernel<<<(E + 255) / 256, 256, 0, stream>>>(dst, deg, E);
    scan_reduce<<<nb, 256, 0, stream>>>(deg, bsum, N);
    scan_bsum<<<1, 256, 0, stream>>>(bsum, nb);
    scan_final<<<nb, 256, 0, stream>>>(deg, bsum, off, pos, N, E);
    bucket_kernel<<<(E + 255) / 256, 256, 0, stream>>>(src, dst, pos, eid, E);

    split_w1<<<(288 * 128 + 255) / 256, 256, 0, stream>>>(W1, w1f_hi, w1f_lo);

    aggregate_kernel<64><<<(N + 3) / 4, 256, 0, stream>>>(x, eid, off, agg, N);
    layer_gemm<64, 64, true><<<(N + 63) / 64, 256, 0, stream>>>(
        agg, x, Wl0, bl0, Wr0, h, N);

    aggregate_kernel<128><<<(N + 3) / 4, 256, 0, stream>>>(h, eid, off, agg, N);
    layer_gemm<128, 128, false><<<(N + 63) / 64, 256, 0, stream>>>(
        agg, h, Wl1, bl1, Wr1, h1, N);

    split_bf16<<<((N * 128 / 4) + 255) / 256, 256, 0, stream>>>(h1, h1_hi, h1_lo, N * 128 / 4);

    classify_mfma<<<(Ef + 127) / 128, 256, 0, stream>>>(
        h1_hi, h1_lo, fsrc, fdst, eattr, w1f_hi, w1f_lo, b1, W2, b2, out, Ef);
}